// Round 4
// baseline (320.963 us; speedup 1.0000x reference)
//
#include <hip/hip_runtime.h>
#include <cmath>

typedef unsigned int uint;
typedef unsigned long long ull;

#define BATCH 32
#define NA 8400
#define NC 80
#define MAXDET 100
#define NMSTHR 0.65f
#define SCTHR 0.01f

#define NT 1024           // NMS threads per block (16 waves) -- r0's proven config
#define NW (NT / 64)
#define EPT 9             // ceil(NA / NT) for key sweep
#define NBINS 4096        // histogram bins on key[31:20]
#define CAP 512           // max candidates per sorted window

__device__ __forceinline__ float stable_sigmoid(float x) {
    if (x >= 0.f) return 1.f / (1.f + expf(-x));
    float e = expf(x);
    return e / (1.f + e);
}

// ---------------- decode: FOUR threads per anchor (r0-exact) ----------------
// Sub-thread q scans channels [20q, 20q+20): 20 independent SCALAR loads
// batched into registers (this exact pattern measured fastest across r0-r3;
// every "fewer instructions" variant regressed), then a 4-lane shfl
// butterfly merges (max, lowest-channel) -> exact jnp.argmax semantics.
// Additions vs r0: per-image key histogram (global atomicAdd, q==0 lanes)
// and per-image max|coord| computed FROM REGISTERS (no wboxes re-read),
// wave-reduced to one atomicMax per wave.
// Returns this thread's |coord| max contribution (0 for q!=0 lanes).
template<int HW, int W, int S>
__device__ __forceinline__ float decode4(
    const float* __restrict__ cls, const float* __restrict__ reg,
    const float* __restrict__ obj, int b, int p, int q, int ag,
    float4* __restrict__ wboxes, int* __restrict__ wlabels, uint* __restrict__ wkeys,
    uint* __restrict__ hist)
{
    const float* cbase = cls + (size_t)b * NC * HW + (size_t)(q * 20) * HW + p;
    float v[20];
    #pragma unroll
    for (int i = 0; i < 20; ++i) v[i] = cbase[(size_t)i * HW];
    float m = v[0]; int c = 0;
    #pragma unroll
    for (int i = 1; i < 20; ++i)
        if (v[i] > m) { m = v[i]; c = i; }     // strict > -> first max in slice
    c += q * 20;

    // merge the 4 sub-threads (lanes 4k..4k+3): tie -> lower channel index
    #pragma unroll
    for (int o = 1; o <= 2; o <<= 1) {
        float om = __shfl_xor(m, o);
        int   oc = __shfl_xor(c, o);
        if (om > m || (om == m && oc < c)) { m = om; c = oc; }
    }

    float mm = 0.f;
    if (q == 0) {
        const float* rb = reg + (size_t)b * 4 * HW + p;
        float r0 = rb[0];
        float r1 = rb[HW];
        float r2 = rb[2 * (size_t)HW];
        float r3 = rb[3 * (size_t)HW];
        float ov = obj[(size_t)b * HW + p];

        int y = p / W;            // W constexpr -> magic mul
        int x = p - y * W;
        float sc = stable_sigmoid(m) * stable_sigmoid(ov);
        float cx = r0 * (float)S + (float)x * (float)S;
        float cy = r1 * (float)S + (float)y * (float)S;
        float bw = expf(r2) * (float)S;
        float bh = expf(r3) * (float)S;
        float x1 = cx - bw * 0.5f, y1 = cy - bh * 0.5f;
        float x2 = cx + bw * 0.5f, y2 = cy + bh * 0.5f;

        wboxes[ag]  = make_float4(x1, y1, x2, y2);
        wlabels[ag] = c;
        uint k = (sc >= SCTHR) ? ~__float_as_uint(sc) : 0xFFFFFFFFu;
        wkeys[ag]   = k;
        mm = fmaxf(fmaxf(fabsf(x1), fabsf(y1)), fmaxf(fabsf(x2), fabsf(y2)));
        if (k != 0xFFFFFFFFu)
            atomicAdd(&hist[(size_t)b * NBINS + (k >> 20)], 1u);
    }
    return mm;
}

__global__ __launch_bounds__(256) void decode_kernel(
    const float* __restrict__ cls0, const float* __restrict__ reg0, const float* __restrict__ obj0,
    const float* __restrict__ cls1, const float* __restrict__ reg1, const float* __restrict__ obj1,
    const float* __restrict__ cls2, const float* __restrict__ reg2, const float* __restrict__ obj2,
    float4* __restrict__ wboxes, int* __restrict__ wlabels, uint* __restrict__ wkeys,
    uint* __restrict__ hist, uint* __restrict__ amax)
{
    int gid = blockIdx.x * blockDim.x + threadIdx.x;   // BATCH*NA*4 threads exactly
    int ag = gid >> 2;       // global anchor id
    int q  = gid & 3;        // channel-slice id
    int b = ag / NA;
    int j = ag - b * NA;

    float mm;
    if (j < 6400)
        mm = decode4<6400, 80, 8>(cls0, reg0, obj0, b, j, q, ag,
                                  wboxes, wlabels, wkeys, hist);
    else if (j < 8000)
        mm = decode4<1600, 40, 16>(cls1, reg1, obj1, b, j - 6400, q, ag,
                                   wboxes, wlabels, wkeys, hist);
    else
        mm = decode4<400, 20, 32>(cls2, reg2, obj2, b, j - 8000, q, ag,
                                  wboxes, wlabels, wkeys, hist);

    // per-image abs-max: 33600 threads/image = 525 waves exactly, so a wave
    // never straddles images -> full-wave reduce + ONE atomic per wave.
    // Positive-float bits are monotone as uint.
    #pragma unroll
    for (int o = 32; o >= 1; o >>= 1) mm = fmaxf(mm, __shfl_xor(mm, o));
    if ((threadIdx.x & 63) == 0) atomicMax(&amax[b], __float_as_uint(mm));
}

// ---------------- NMS via sorted walk (exact greedy-NMS equivalence) ----------------
// Prework (offset max, histogram) arrives precomputed from decode; this
// kernel only: scans the precomputed 4096-bin histogram (uint4/thread),
// compacts the window's candidates, sorts CAP=512 keys, prefetches
// candidate boxes into LDS in parallel, then runs the serial wave-0 walk
// entirely out of LDS.
__global__ __launch_bounds__(NT) void nms_kernel(
    const float4* __restrict__ wboxes, const int* __restrict__ wlabels,
    const uint* __restrict__ wkeys, const uint* __restrict__ hist,
    const uint* __restrict__ amax, float* __restrict__ out)
{
    int b = blockIdx.x;
    int t = threadIdx.x;
    int lane = t & 63;
    int wv = t >> 6;
    const float4* boxes  = wboxes  + (size_t)b * NA;
    const int*    labels = wlabels + (size_t)b * NA;
    const uint*   keys   = wkeys   + (size_t)b * NA;
    const uint*   h      = hist    + (size_t)b * NBINS;

    __shared__ uint   s_cum[NBINS + 1];     // exclusive prefix
    __shared__ uint   s_wsum[NW];
    __shared__ ull    s_skey[CAP];
    __shared__ float4 s_cbox[CAP];          // candidate OFFSET boxes
    __shared__ float  s_ca[CAP];            // candidate offset-box areas
    __shared__ int    s_clb[CAP];           // candidate labels
    __shared__ float  s_kbox[MAXDET][4];    // kept OFFSET boxes
    __shared__ float  s_ka1[MAXDET];
    __shared__ int    s_kidx[MAXDET];
    __shared__ float  s_kscr[MAXDET];
    __shared__ int    s_klab[MAXDET];
    __shared__ float  s_off;
    __shared__ int    s_kept, s_winlo, s_winhi, s_nsel;

    // ---- load precomputed histogram (uint4/thread) + exclusive scan ----
    uint4 hv = *(const uint4*)(h + 4 * t);
    uint l0 = hv.x, l1 = hv.y, l2 = hv.z, l3 = hv.w;
    uint L = l0 + l1 + l2 + l3;
    uint ls = L;
    #pragma unroll
    for (int o = 1; o < 64; o <<= 1) {
        uint v = __shfl_up(ls, o);
        if (lane >= o) ls += v;
    }
    if (lane == 63) s_wsum[wv] = ls;
    if (t == 0) {
        s_kept = 0; s_winlo = 0;
        s_off = __uint_as_float(amax[b]) + 1.f;
    }
    __syncthreads();
    if (t < NW) {
        uint v = s_wsum[t];
        uint vs = v;
        #pragma unroll
        for (int o = 1; o < NW; o <<= 1) {
            uint u = __shfl_up(vs, o);
            if (t >= o) vs += u;
        }
        s_wsum[t] = vs - v;
    }
    __syncthreads();
    uint base = s_wsum[wv] + (ls - L);
    s_cum[4 * t]     = base;
    s_cum[4 * t + 1] = base + l0;
    s_cum[4 * t + 2] = base + l0 + l1;
    s_cum[4 * t + 3] = base + l0 + l1 + l2;
    if (t == NT - 1) s_cum[NBINS] = base + L;

    // ---- window loop (typically runs once) ----
    for (;;) {
        __syncthreads();
        int kept = s_kept, winlo = s_winlo;
        uint remaining = s_cum[NBINS] - s_cum[winlo];
        if (kept >= MAXDET || winlo >= NBINS || remaining == 0u) break;
        if (t == 0) { s_winhi = winlo + 1; s_nsel = 0; }   // giant-bin clamp floor
        if (t < CAP) s_skey[t] = ~0ull;
        __syncthreads();
        // winhi via unique-boundary store: pred(i) = cum[i+1]-cl <= CAP is
        // monotone non-increasing in i -> exactly one boundary writer.
        uint cl = s_cum[winlo];
        #pragma unroll
        for (int qq = 0; qq < 4; ++qq) {
            int i = t + qq * NT;
            if (i >= winlo && i < NBINS) {
                bool p0 = (s_cum[i + 1] - cl) <= (uint)CAP;
                bool p1 = (i + 1 < NBINS) && ((s_cum[i + 2] - cl) <= (uint)CAP);
                if (p0 && !p1) s_winhi = i + 1;   // unique writer
            }
        }
        __syncthreads();
        int winhi = s_winhi;

        // wave-aggregated compaction of window candidates (keys L2-hot)
        #pragma unroll
        for (int w = 0; w < EPT; ++w) {
            int e = t + w * NT;
            bool qf = false;
            uint k = 0;
            if (e < NA) {
                k = keys[e];
                if (k != 0xFFFFFFFFu) {
                    int bin = (int)(k >> 20);
                    qf = (bin >= winlo && bin < winhi);
                }
            }
            ull mask = __ballot(qf);
            if (mask) {
                int leader = __ffsll(mask) - 1;
                int pbase = 0;
                if (lane == leader) pbase = atomicAdd(&s_nsel, __popcll(mask));
                pbase = __shfl(pbase, leader);
                if (qf) {
                    int pos = pbase + __popcll(mask & ((1ull << lane) - 1ull));
                    if (pos < CAP) s_skey[pos] = ((ull)k << 32) | (uint)e;
                }
            }
        }
        __syncthreads();
        int nsel = s_nsel; if (nsel > CAP) nsel = CAP;

        // hybrid bitonic sort of CAP=512 ull keys ascending: j<64 passes are
        // intra-wave shfl_xor (no barrier); j>=64 via LDS (barriered).
        ull k = (t < CAP) ? s_skey[t] : ~0ull;
        for (int k2 = 2; k2 <= CAP; k2 <<= 1) {
            for (int j = k2 >> 1; j > 0; j >>= 1) {
                if (j >= 64) {
                    if (t < CAP) s_skey[t] = k;
                    __syncthreads();
                    if (t < CAP) {
                        ull kp = s_skey[t ^ j];
                        bool low = (t & j) == 0;
                        bool up  = (t & k2) == 0;
                        k = ((k < kp) == (low == up)) ? k : kp;
                    }
                    __syncthreads();
                } else if (t < CAP) {
                    ull kp = __shfl_xor(k, j);
                    bool low = (t & j) == 0;
                    bool up  = (t & k2) == 0;
                    k = ((k < kp) == (low == up)) ? k : kp;
                }
            }
        }
        if (t < CAP) s_skey[t] = k;
        __syncthreads();

        // parallel candidate prefetch: scattered global reads done ONCE in
        // parallel; the serial walk below touches only LDS.
        float off = s_off;
        if (t < nsel) {
            ull sk = s_skey[t];
            if (sk != ~0ull) {
                int idx = (int)(sk & 0xFFFFFFFFull);
                float4 rb = boxes[idx];
                int lb = labels[idx];
                float lo = (float)lb * off;
                float c0 = rb.x + lo, c1 = rb.y + lo;
                float c2 = rb.z + lo, c3 = rb.w + lo;
                s_cbox[t] = make_float4(c0, c1, c2, c3);
                s_ca[t]   = (c2 - c0) * (c3 - c1);
                s_clb[t]  = lb;
            }
        }
        __syncthreads();

        // sorted walk on wave 0 (exact reference IoU + compare)
        if (t < 64) {
            int kept2 = s_kept;
            for (int cb = 0; cb < nsel && kept2 < MAXDET; cb += 64) {
                int ci = cb + lane;
                ull sk = (ci < nsel) ? s_skey[ci] : ~0ull;
                bool has = (sk != ~0ull);
                int idx = 0, lab = 0;
                float sc = 0.f, c0 = 0.f, c1 = 0.f, c2 = 0.f, c3 = 0.f, ca = 0.f;
                if (has) {
                    idx = (int)(sk & 0xFFFFFFFFull);
                    sc  = __uint_as_float(~(uint)(sk >> 32));   // exact score bits
                    float4 cbx = s_cbox[ci];
                    c0 = cbx.x; c1 = cbx.y; c2 = cbx.z; c3 = cbx.w;
                    ca = s_ca[ci];
                    lab = s_clb[ci];
                    for (int qq = 0; qq < kept2; ++qq) {
                        float tlx = fmaxf(s_kbox[qq][0], c0);
                        float tly = fmaxf(s_kbox[qq][1], c1);
                        float brx = fminf(s_kbox[qq][2], c2);
                        float bry = fminf(s_kbox[qq][3], c3);
                        float ww = fmaxf(brx - tlx, 0.f);
                        float hh = fmaxf(bry - tly, 0.f);
                        float inter = ww * hh;
                        float iou = inter / (s_ka1[qq] + ca - inter + 1e-6f);
                        if (iou > NMSTHR) { has = false; break; }
                    }
                }
                ull am = __ballot(has);
                while (am && kept2 < MAXDET) {
                    int f = __ffsll(am) - 1;
                    float f0 = __shfl(c0, f), f1 = __shfl(c1, f);
                    float f2 = __shfl(c2, f), f3 = __shfl(c3, f);
                    float fa = __shfl(ca, f);
                    int   fidx = __shfl(idx, f);
                    int   flab = __shfl(lab, f);
                    float fsc  = __shfl(sc, f);
                    if (lane == 0) {
                        s_kbox[kept2][0] = f0; s_kbox[kept2][1] = f1;
                        s_kbox[kept2][2] = f2; s_kbox[kept2][3] = f3;
                        s_ka1[kept2] = fa; s_kidx[kept2] = fidx;
                        s_kscr[kept2] = fsc; s_klab[kept2] = flab;
                    }
                    kept2++;
                    if (lane == f) has = false;
                    if (has) {
                        float tlx = fmaxf(f0, c0), tly = fmaxf(f1, c1);
                        float brx = fminf(f2, c2), bry = fminf(f3, c3);
                        float ww = fmaxf(brx - tlx, 0.f), hh = fmaxf(bry - tly, 0.f);
                        float inter = ww * hh;
                        float iou = inter / (fa + ca - inter + 1e-6f);
                        if (iou > NMSTHR) has = false;
                    }
                    am = __ballot(has);
                }
            }
            if (lane == 0) s_kept = kept2;
        }
        __syncthreads();
        if (t == 0) s_winlo = s_winhi;
    }
    __syncthreads();

    // ---- epilogue: boxes/scores/labels/valid (fp32) ----
    if (t < MAXDET) {
        int kept = s_kept;
        float4 obx = make_float4(0.f, 0.f, 0.f, 0.f);
        float osc = 0.f, olab = -1.f, oval = 0.f;
        if (t < kept) {
            int idx = s_kidx[t];
            obx  = boxes[idx];              // raw (non-offset) box
            osc  = s_kscr[t];
            olab = (float)s_klab[t];
            oval = 1.f;
        }
        float* ob = out + ((size_t)b * MAXDET + t) * 4;
        ob[0] = obx.x; ob[1] = obx.y; ob[2] = obx.z; ob[3] = obx.w;
        out[BATCH * MAXDET * 4 + b * MAXDET + t] = osc;
        out[BATCH * MAXDET * 5 + b * MAXDET + t] = olab;
        out[BATCH * MAXDET * 6 + b * MAXDET + t] = oval;
    }
}

extern "C" void kernel_launch(void* const* d_in, const int* in_sizes, int n_in,
                              void* d_out, int out_size, void* d_ws, size_t ws_size,
                              hipStream_t stream) {
    // setup_inputs() dict order: cls0, reg0, obj0, cls1, reg1, obj1, cls2, reg2, obj2
    const float* cls0 = (const float*)d_in[0];
    const float* reg0 = (const float*)d_in[1];
    const float* obj0 = (const float*)d_in[2];
    const float* cls1 = (const float*)d_in[3];
    const float* reg1 = (const float*)d_in[4];
    const float* obj1 = (const float*)d_in[5];
    const float* cls2 = (const float*)d_in[6];
    const float* reg2 = (const float*)d_in[7];
    const float* obj2 = (const float*)d_in[8];

    // ws layout: boxes | labels | keys | hist | amax
    char* ws = (char*)d_ws;
    size_t nBA = (size_t)BATCH * NA;
    float4* wboxes  = (float4*)ws;
    int*    wlabels = (int*)(ws + nBA * 16);
    uint*   wkeys   = (uint*)(ws + nBA * 20);
    uint*   whist   = (uint*)(ws + nBA * 24);
    uint*   wamax   = (uint*)(ws + nBA * 24 + (size_t)BATCH * NBINS * 4);

    // zero hist + amax (graph-capturable stream memset)
    hipMemsetAsync(whist, 0, (size_t)BATCH * NBINS * 4 + 128, stream);

    int total = BATCH * NA * 4;   // 1,075,200 = 4200 * 256 exactly
    decode_kernel<<<total / 256, 256, 0, stream>>>(
        cls0, reg0, obj0, cls1, reg1, obj1, cls2, reg2, obj2,
        wboxes, wlabels, wkeys, whist, wamax);

    nms_kernel<<<BATCH, NT, 0, stream>>>(wboxes, wlabels, wkeys, whist, wamax,
                                         (float*)d_out);
}

// Round 5
// 172.591 us; speedup vs baseline: 1.8597x; 1.8597x over previous
//
#include <hip/hip_runtime.h>
#include <cmath>

typedef unsigned int uint;
typedef unsigned long long ull;

#define BATCH 32
#define NA 8400
#define NC 80
#define MAXDET 100
#define NMSTHR 0.65f
#define SCTHR 0.01f
#define NEG_INF (-INFINITY)

#define NT 1024         // NMS threads per block
#define NW (NT / 64)
#define EPT 9           // ceil(NA / NT)
#define NBINS 4096      // histogram bins on key[31:20]
#define CAP 512         // max candidates per sorted window

__device__ __forceinline__ float stable_sigmoid(float x) {
    if (x >= 0.f) return 1.f / (1.f + expf(-x));
    float e = expf(x);
    return e / (1.f + e);
}

// ---------------- decode: FOUR threads per anchor (r0-EXACT) ----------------
// Sub-thread q scans channels [20q, 20q+20): 20 independent loads batched
// into registers (deep memory-level parallelism), then a 4-lane shfl
// butterfly merges (max, lowest-channel) -> exact jnp.argmax semantics.
// NOTE: r4 added a return value + hist/amax atomics to this function and the
// compiler collapsed the allocation to 20 VGPRs, serializing the 20 loads
// (176 us vs <54 us). Keep this function tail-free and store-only.
template<int HW, int W, int S>
__device__ __forceinline__ void decode4(
    const float* __restrict__ cls, const float* __restrict__ reg,
    const float* __restrict__ obj, int b, int p, int q, int ag,
    float4* __restrict__ wboxes, int* __restrict__ wlabels, uint* __restrict__ wkeys)
{
    const float* cbase = cls + (size_t)b * NC * HW + (size_t)(q * 20) * HW + p;
    float v[20];
    #pragma unroll
    for (int i = 0; i < 20; ++i) v[i] = cbase[(size_t)i * HW];
    float m = v[0]; int c = 0;
    #pragma unroll
    for (int i = 1; i < 20; ++i)
        if (v[i] > m) { m = v[i]; c = i; }     // strict > -> first max in slice
    c += q * 20;

    // merge the 4 sub-threads (lanes 4k..4k+3): tie -> lower channel index
    #pragma unroll
    for (int o = 1; o <= 2; o <<= 1) {
        float om = __shfl_xor(m, o);
        int   oc = __shfl_xor(c, o);
        if (om > m || (om == m && oc < c)) { m = om; c = oc; }
    }

    if (q == 0) {
        const float* rb = reg + (size_t)b * 4 * HW + p;
        float r0 = rb[0];
        float r1 = rb[HW];
        float r2 = rb[2 * (size_t)HW];
        float r3 = rb[3 * (size_t)HW];
        float ov = obj[(size_t)b * HW + p];

        int y = p / W;            // W constexpr -> magic mul
        int x = p - y * W;
        float sc = stable_sigmoid(m) * stable_sigmoid(ov);
        float cx = r0 * (float)S + (float)x * (float)S;
        float cy = r1 * (float)S + (float)y * (float)S;
        float bw = expf(r2) * (float)S;
        float bh = expf(r3) * (float)S;

        wboxes[ag]  = make_float4(cx - bw * 0.5f, cy - bh * 0.5f,
                                  cx + bw * 0.5f, cy + bh * 0.5f);
        wlabels[ag] = c;
        wkeys[ag]   = (sc >= SCTHR) ? ~__float_as_uint(sc) : 0xFFFFFFFFu;
    }
}

__global__ __launch_bounds__(256) void decode_kernel(
    const float* __restrict__ cls0, const float* __restrict__ reg0, const float* __restrict__ obj0,
    const float* __restrict__ cls1, const float* __restrict__ reg1, const float* __restrict__ obj1,
    const float* __restrict__ cls2, const float* __restrict__ reg2, const float* __restrict__ obj2,
    float4* __restrict__ wboxes, int* __restrict__ wlabels, uint* __restrict__ wkeys)
{
    int gid = blockIdx.x * blockDim.x + threadIdx.x;   // BATCH*NA*4 threads exactly
    int ag = gid >> 2;       // global anchor id
    int q  = gid & 3;        // channel-slice id
    int b = ag / NA;
    int j = ag - b * NA;

    if (j < 6400)
        decode4<6400, 80, 8>(cls0, reg0, obj0, b, j, q, ag, wboxes, wlabels, wkeys);
    else if (j < 8000)
        decode4<1600, 40, 16>(cls1, reg1, obj1, b, j - 6400, q, ag, wboxes, wlabels, wkeys);
    else
        decode4<400, 20, 32>(cls2, reg2, obj2, b, j - 8000, q, ag, wboxes, wlabels, wkeys);
}

// ---------------- NMS via sorted walk (exact greedy-NMS equivalence) ----------------
// r0's measured-54us kernel with ONE change: after the sort, all 1024
// threads prefetch the <=512 candidate boxes/areas/labels into LDS in
// parallel, so the serial wave-0 walk touches only LDS (r0 issued the
// scattered global box/label loads inside the serial section).
__global__ __launch_bounds__(NT) void nms_kernel(
    const float4* __restrict__ wboxes, const int* __restrict__ wlabels,
    const uint* __restrict__ wkeys, float* __restrict__ out)
{
    int b = blockIdx.x;
    int t = threadIdx.x;
    int lane = t & 63;
    int wv = t >> 6;
    const float4* boxes  = wboxes  + (size_t)b * NA;
    const int*    labels = wlabels + (size_t)b * NA;
    const uint*   keys   = wkeys   + (size_t)b * NA;

    __shared__ uint   s_hist[NBINS];
    __shared__ uint   s_cum[NBINS + 1];    // exclusive prefix
    __shared__ uint   s_wsum[NW];
    __shared__ ull    s_skey[CAP];
    __shared__ float4 s_cbox[CAP];         // candidate OFFSET boxes (prefetched)
    __shared__ float  s_ca[CAP];           // candidate offset-box areas
    __shared__ int    s_clb[CAP];          // candidate labels
    __shared__ float  s_kbox[MAXDET][4];   // kept OFFSET boxes
    __shared__ float  s_ka1[MAXDET];
    __shared__ int    s_kidx[MAXDET];
    __shared__ float  s_kscr[MAXDET];
    __shared__ int    s_klab[MAXDET];
    __shared__ float  s_red[NW];
    __shared__ float  s_off;
    __shared__ int    s_kept, s_winlo, s_winhi, s_nsel;

    // ---- offset = max|coord| over ALL boxes + 1 (boxes are L2/L3-hot) ----
    float m = 0.f;
    #pragma unroll
    for (int w = 0; w < EPT; ++w) {
        int e = t + w * NT;
        if (e < NA) {
            float4 v = boxes[e];
            m = fmaxf(m, fmaxf(fmaxf(fabsf(v.x), fabsf(v.y)),
                               fmaxf(fabsf(v.z), fabsf(v.w))));
        }
    }
    #pragma unroll
    for (int o = 32; o >= 1; o >>= 1) m = fmaxf(m, __shfl_xor(m, o));
    if (lane == 0) s_red[wv] = m;
    // ---- LDS histogram of precomputed keys ----
    for (int i = t; i < NBINS; i += NT) s_hist[i] = 0;
    if (t == 0) { s_kept = 0; s_winlo = 0; }
    __syncthreads();
    if (t == 0) {
        float mm = 0.f;
        for (int w = 0; w < NW; ++w) mm = fmaxf(mm, s_red[w]);
        s_off = mm + 1.f;
    }
    #pragma unroll
    for (int w = 0; w < EPT; ++w) {
        int e = t + w * NT;
        if (e < NA) {
            uint k = keys[e];
            if (k != 0xFFFFFFFFu) atomicAdd(&s_hist[k >> 20], 1u);
        }
    }
    __syncthreads();
    float off = s_off;

    // ---- exclusive scan over 4096 bins: 4 bins/thread + shfl scans ----
    uint l0 = s_hist[4 * t], l1 = s_hist[4 * t + 1],
         l2 = s_hist[4 * t + 2], l3 = s_hist[4 * t + 3];
    uint L = l0 + l1 + l2 + l3;
    uint ls = L;
    #pragma unroll
    for (int o = 1; o < 64; o <<= 1) {
        uint v = __shfl_up(ls, o);
        if (lane >= o) ls += v;
    }
    if (lane == 63) s_wsum[wv] = ls;
    __syncthreads();
    if (t < NW) {
        uint v = s_wsum[t];
        uint vs = v;
        #pragma unroll
        for (int o = 1; o < NW; o <<= 1) {
            uint u = __shfl_up(vs, o);
            if ((t & 63) >= o) vs += u;
        }
        s_wsum[t] = vs - v;
    }
    __syncthreads();
    uint base = s_wsum[wv] + (ls - L);
    s_cum[4 * t]     = base;
    s_cum[4 * t + 1] = base + l0;
    s_cum[4 * t + 2] = base + l0 + l1;
    s_cum[4 * t + 3] = base + l0 + l1 + l2;
    if (t == NT - 1) s_cum[NBINS] = base + L;

    // ---- window loop (typically runs once) ----
    for (;;) {
        __syncthreads();
        int kept = s_kept, winlo = s_winlo;
        uint remaining = s_cum[NBINS] - s_cum[winlo];
        if (kept >= MAXDET || winlo >= NBINS || remaining == 0u) break;
        if (t == 0) { s_winhi = winlo + 1; s_nsel = 0; }   // giant-bin clamp floor
        if (t < CAP) s_skey[t] = ~0ull;
        __syncthreads();
        // winhi via unique-boundary store: pred(i) = cum[i+1]-cl <= CAP is
        // monotone non-increasing in i, so exactly one i has pred(i) && !pred(i+1).
        uint cl = s_cum[winlo];
        #pragma unroll
        for (int q = 0; q < 4; ++q) {
            int i = t + q * NT;
            if (i >= winlo && i < NBINS) {
                bool p0 = (s_cum[i + 1] - cl) <= (uint)CAP;
                bool p1 = (i + 1 < NBINS) && ((s_cum[i + 2] - cl) <= (uint)CAP);
                if (p0 && !p1) s_winhi = i + 1;   // unique writer
            }
        }
        __syncthreads();
        int winhi = s_winhi;

        // wave-aggregated compaction of window candidates (keys from global, L2-hot)
        #pragma unroll
        for (int w = 0; w < EPT; ++w) {
            int e = t + w * NT;
            bool q = false;
            uint k = 0;
            if (e < NA) {
                k = keys[e];
                if (k != 0xFFFFFFFFu) {
                    int bin = (int)(k >> 20);
                    q = (bin >= winlo && bin < winhi);
                }
            }
            ull mask = __ballot(q);
            if (mask) {
                int leader = __ffsll(mask) - 1;
                int pbase = 0;
                if (lane == leader) pbase = atomicAdd(&s_nsel, __popcll(mask));
                pbase = __shfl(pbase, leader);
                if (q) {
                    int pos = pbase + __popcll(mask & ((1ull << lane) - 1ull));
                    if (pos < CAP) s_skey[pos] = ((ull)k << 32) | (uint)e;
                }
            }
        }
        __syncthreads();
        int nsel = s_nsel; if (nsel > CAP) nsel = CAP;

        // hybrid bitonic sort of CAP=512 ull keys ascending: j<64 passes are
        // intra-wave shfl_xor (no barrier); j>=64 via LDS (6 barriered passes).
        ull k = (t < CAP) ? s_skey[t] : ~0ull;
        for (int k2 = 2; k2 <= CAP; k2 <<= 1) {
            for (int j = k2 >> 1; j > 0; j >>= 1) {
                if (j >= 64) {
                    if (t < CAP) s_skey[t] = k;
                    __syncthreads();
                    if (t < CAP) {
                        ull kp = s_skey[t ^ j];
                        bool low = (t & j) == 0;
                        bool up  = (t & k2) == 0;
                        k = ((k < kp) == (low == up)) ? k : kp;
                    }
                    __syncthreads();
                } else if (t < CAP) {
                    ull kp = __shfl_xor(k, j);
                    bool low = (t & j) == 0;
                    bool up  = (t & k2) == 0;
                    k = ((k < kp) == (low == up)) ? k : kp;
                }
            }
        }
        if (t < CAP) s_skey[t] = k;
        __syncthreads();

        // parallel candidate prefetch: scattered global reads done ONCE by
        // all 1024 threads; the serial walk below touches only LDS.
        if (t < nsel) {
            ull sk = s_skey[t];
            if (sk != ~0ull) {
                int idx = (int)(sk & 0xFFFFFFFFull);
                float4 rb = boxes[idx];
                int lb = labels[idx];
                float lo = (float)lb * off;
                float c0 = rb.x + lo, c1 = rb.y + lo;
                float c2 = rb.z + lo, c3 = rb.w + lo;
                s_cbox[t] = make_float4(c0, c1, c2, c3);
                s_ca[t]   = (c2 - c0) * (c3 - c1);
                s_clb[t]  = lb;
            }
        }
        __syncthreads();

        // sorted walk on wave 0 (exact reference IoU + compare)
        if (t < 64) {
            int kept2 = s_kept;
            for (int cb = 0; cb < nsel && kept2 < MAXDET; cb += 64) {
                int ci = cb + lane;
                ull sk = (ci < nsel) ? s_skey[ci] : ~0ull;
                bool has = (sk != ~0ull);
                int idx = 0, lab = 0;
                float sc = 0.f, c0 = 0.f, c1 = 0.f, c2 = 0.f, c3 = 0.f, ca = 0.f;
                if (has) {
                    idx = (int)(sk & 0xFFFFFFFFull);
                    sc  = __uint_as_float(~(uint)(sk >> 32));   // exact score bits
                    float4 cbx = s_cbox[ci];
                    c0 = cbx.x; c1 = cbx.y; c2 = cbx.z; c3 = cbx.w;
                    ca = s_ca[ci];
                    lab = s_clb[ci];
                    for (int q = 0; q < kept2; ++q) {
                        float tlx = fmaxf(s_kbox[q][0], c0);
                        float tly = fmaxf(s_kbox[q][1], c1);
                        float brx = fminf(s_kbox[q][2], c2);
                        float bry = fminf(s_kbox[q][3], c3);
                        float ww = fmaxf(brx - tlx, 0.f);
                        float hh = fmaxf(bry - tly, 0.f);
                        float inter = ww * hh;
                        float iou = inter / (s_ka1[q] + ca - inter + 1e-6f);
                        if (iou > NMSTHR) { has = false; break; }
                    }
                }
                ull am = __ballot(has);
                while (am && kept2 < MAXDET) {
                    int f = __ffsll(am) - 1;
                    float f0 = __shfl(c0, f), f1 = __shfl(c1, f);
                    float f2 = __shfl(c2, f), f3 = __shfl(c3, f);
                    float fa = __shfl(ca, f);
                    int   fidx = __shfl(idx, f);
                    int   flab = __shfl(lab, f);
                    float fsc  = __shfl(sc, f);
                    if (lane == 0) {
                        s_kbox[kept2][0] = f0; s_kbox[kept2][1] = f1;
                        s_kbox[kept2][2] = f2; s_kbox[kept2][3] = f3;
                        s_ka1[kept2] = fa; s_kidx[kept2] = fidx;
                        s_kscr[kept2] = fsc; s_klab[kept2] = flab;
                    }
                    kept2++;
                    if (lane == f) has = false;
                    if (has) {
                        float tlx = fmaxf(f0, c0), tly = fmaxf(f1, c1);
                        float brx = fminf(f2, c2), bry = fminf(f3, c3);
                        float ww = fmaxf(brx - tlx, 0.f), hh = fmaxf(bry - tly, 0.f);
                        float inter = ww * hh;
                        float iou = inter / (fa + ca - inter + 1e-6f);
                        if (iou > NMSTHR) has = false;
                    }
                    am = __ballot(has);
                }
            }
            if (lane == 0) s_kept = kept2;
        }
        __syncthreads();
        if (t == 0) s_winlo = s_winhi;
    }
    __syncthreads();

    // ---- epilogue: boxes/scores/labels/valid (fp32) ----
    if (t < MAXDET) {
        int kept = s_kept;
        float4 obx = make_float4(0.f, 0.f, 0.f, 0.f);
        float osc = 0.f, olab = -1.f, oval = 0.f;
        if (t < kept) {
            int idx = s_kidx[t];
            obx  = boxes[idx];              // raw (non-offset) box
            osc  = s_kscr[t];
            olab = (float)s_klab[t];
            oval = 1.f;
        }
        float* ob = out + ((size_t)b * MAXDET + t) * 4;
        ob[0] = obx.x; ob[1] = obx.y; ob[2] = obx.z; ob[3] = obx.w;
        out[BATCH * MAXDET * 4 + b * MAXDET + t] = osc;
        out[BATCH * MAXDET * 5 + b * MAXDET + t] = olab;
        out[BATCH * MAXDET * 6 + b * MAXDET + t] = oval;
    }
}

extern "C" void kernel_launch(void* const* d_in, const int* in_sizes, int n_in,
                              void* d_out, int out_size, void* d_ws, size_t ws_size,
                              hipStream_t stream) {
    // setup_inputs() dict order: cls0, reg0, obj0, cls1, reg1, obj1, cls2, reg2, obj2
    const float* cls0 = (const float*)d_in[0];
    const float* reg0 = (const float*)d_in[1];
    const float* obj0 = (const float*)d_in[2];
    const float* cls1 = (const float*)d_in[3];
    const float* reg1 = (const float*)d_in[4];
    const float* obj1 = (const float*)d_in[5];
    const float* cls2 = (const float*)d_in[6];
    const float* reg2 = (const float*)d_in[7];
    const float* obj2 = (const float*)d_in[8];

    // ws layout: boxes | labels | keys
    char* ws = (char*)d_ws;
    size_t nBA = (size_t)BATCH * NA;
    float4* wboxes  = (float4*)ws;
    int*    wlabels = (int*)(ws + nBA * 16);
    uint*   wkeys   = (uint*)(ws + nBA * 20);

    int total = BATCH * NA * 4;   // 1,075,200 = 4200 * 256 exactly
    decode_kernel<<<total / 256, 256, 0, stream>>>(
        cls0, reg0, obj0, cls1, reg1, obj1, cls2, reg2, obj2,
        wboxes, wlabels, wkeys);

    nms_kernel<<<BATCH, NT, 0, stream>>>(wboxes, wlabels, wkeys, (float*)d_out);
}